// Round 10
// baseline (44.697 us; speedup 1.0000x reference)
//
#include <hip/hip_runtime.h>
#include <math.h>

#define NPIX (8 * 256 * 256)   // B*H*W
#define CC 16                  // C
#define KK 8                   // K classes
#define TPB 256                // 4 independent waves
#define NTILES 16              // 16-px tiles per wave -> 256 px/wave, 1024 px/block
#define GRID (NPIX / 1024)     // 512 blocks = 2 resident/CU

typedef __attribute__((ext_vector_type(8))) short short8;  // 8 bf16 (4 VGPRs)
typedef __attribute__((ext_vector_type(4))) float f32x4;

#if __has_builtin(__builtin_amdgcn_exp2f)
#define EXP2F(v) __builtin_amdgcn_exp2f(v)
#else
#define EXP2F(v) exp2f(v)
#endif

// ---------------- control kernel (diagnostic): same traffic, no math ----------------
// Reads x in the same 64B/px strided float4 pattern, writes the same 96B/px record
// pattern (48 MiB) into d_ws. T_control = dur_new - 24.0us isolates the memory path.
__global__ __launch_bounds__(256) void ctrl_kernel(const float* __restrict__ x,
                                                   float* __restrict__ ws) {
    const size_t p = (size_t)blockIdx.x * 256 + threadIdx.x;
    const float4* xp = reinterpret_cast<const float4*>(x + p * 16);
    const float4 a = xp[0], b = xp[1], c = xp[2], d = xp[3];
    float4* wp = reinterpret_cast<float4*>(ws + p * 24);
    wp[0] = a; wp[1] = b; wp[2] = c; wp[3] = d;
    wp[4] = make_float4(a.x + b.x, a.y + b.y, a.z + b.z, a.w + b.w);
    wp[5] = make_float4(c.x + d.x, c.y + d.y, c.z + d.z, c.w + d.w);
}

// ---------------- real kernel: byte-identical to R9 ----------------
// prob_k = exp2(c0_k - sum_i z_i^2), z = SC*Linv*x - SC*Linv*mean,
// z via MFMA(A1,[x_hi,x_lo]) + MFMA(A2,[x_hi,1.0]);  SC = sqrt(0.5*log2 e).
// A1 = [W_hi,W_hi]; A2 = [W_lo, biasslot] (bias hi/lo in g==0, f<2 odd slots).

__global__ __launch_bounds__(TPB, 2) void fuzzy_kernel(const float* __restrict__ x,
                                                       const float* __restrict__ mean,
                                                       const float* __restrict__ st,
                                                       float* __restrict__ out) {
    __shared__ float linv[KK][CC][CC + 1];   // unscaled tril inverse
    __shared__ float bias[KK][CC];           // -SC*(Linv*mean)
    __shared__ int4  a1buf[KK * 64];
    __shared__ int4  a2buf[KK * 64];
    __shared__ float c0buf[KK];
    __shared__ f32x4 stgv[4][192];           // per-wave store staging: 32px * 96B

    const int t = threadIdx.x, lane = t & 63, wid = t >> 6;

    // ---- setup phase A: tril inverse (t<128); c0 (t=128..135) ----
    if (t < 128) {
        const int k = t >> 4, j = t & 15;
        const float* L = st + k * CC * CC;
        float col[CC];
#pragma unroll
        for (int i = 0; i < CC; ++i) {
            float s = (i == j) ? 1.0f : 0.0f;
#pragma unroll
            for (int m = 0; m < i; ++m) s = fmaf(-L[i * CC + m], col[m], s);
            col[i] = (i < j) ? 0.0f : s / L[i * CC + i];
            linv[k][i][j] = col[i];
        }
    } else if (t < 128 + KK) {
        const int k = t - 128;
        const float* Lk = st + k * CC * CC;
        float ld = 0.0f;
#pragma unroll
        for (int i = 0; i < CC; ++i) ld += __logf(fabsf(Lk[i * CC + i]));
        c0buf[k] = (-14.70301653f - ld) * 1.44269504f;  // -0.5*16*ln(2pi), log2(e)
    }
    __syncthreads();

    const float SCALE = 0.8493218891f;       // sqrt(0.5*log2(e))
    // ---- setup phase B1: bias rows (t<128) ----
    if (t < 128) {
        const int k = t >> 4, j = t & 15;
        float b = 0.0f;
#pragma unroll
        for (int j2 = 0; j2 < CC; ++j2) b = fmaf(linv[k][j][j2], mean[k * CC + j2], b);
        bias[k][j] = -b * SCALE;
    }
    __syncthreads();

    // ---- setup phase B2: pack fragments, 2 slots per thread ----
#pragma unroll
    for (int q = 0; q < 2; ++q) {
        const int idx = t * 2 + q;
        const int kk2 = idx >> 6, l = idx & 63;
        const int i = l & 15, gg = l >> 4;
        int a1d[4], a2d[4];
#pragma unroll
        for (int f = 0; f < 4; ++f) {
            const float w = SCALE * linv[kk2][i][4 * gg + f];
            const unsigned wb = __float_as_uint(w) & 0xFFFF0000u;
            const unsigned hb = wb >> 16;
            a1d[f] = (int)(hb | (hb << 16));                       // [W_hi, W_hi]
            const float wl = w - __uint_as_float(wb);
            unsigned odd = 0u;
            if (gg == 0 && f < 2) {                                // bias hi/lo slots
                const float b = bias[kk2][i];
                const unsigned bb = __float_as_uint(b) & 0xFFFF0000u;
                if (f == 0) odd = bb >> 16;
                else        odd = __float_as_uint(b - __uint_as_float(bb)) >> 16;
            }
            a2d[f] = (int)((__float_as_uint(wl) >> 16) | (odd << 16));  // [W_lo, bias]
        }
        a1buf[idx] = make_int4(a1d[0], a1d[1], a1d[2], a1d[3]);
        a2buf[idx] = make_int4(a2d[0], a2d[1], a2d[2], a2d[3]);
    }
    __syncthreads();

    // ---- hoist A fragments + c0 into registers ----
    short8 A1[KK], A2[KK];
    float c0v[KK];
#pragma unroll
    for (int k = 0; k < KK; ++k) {
        A1[k]  = __builtin_bit_cast(short8, a1buf[k * 64 + lane]);
        A2[k]  = __builtin_bit_cast(short8, a2buf[k * 64 + lane]);
        c0v[k] = c0buf[k];
    }

    const int p = lane & 15, g = lane >> 4;
    const size_t wbase = (size_t)blockIdx.x * 1024 + (size_t)wid * 256;  // wave pixel base
    const float* xptr = x + (wbase + p) * CC + g * 4;                    // + tt*256
    float* obase = out + wbase * 24 + (size_t)lane * 4;                  // lane-linear store base
    f32x4* sw = stgv[wid];

    float4 xf0 = *(const float4*)(xptr);
    float4 xf1 = *(const float4*)(xptr + 256);

#pragma unroll
    for (int pi = 0; pi < NTILES / 2; ++pi) {
#pragma unroll
        for (int sub = 0; sub < 2; ++sub) {
            const int tt = 2 * pi + sub;
            const float4 xf2 = (tt + 2 < NTILES) ? *(const float4*)(xptr + (size_t)(tt + 2) * 256) : xf0;

            const int pp = sub * 16 + p;          // pixel within the 32-px pair
            sw[6 * pp + g] = __builtin_bit_cast(f32x4, xf0);   // stage x passthrough

            // pack B1 = [x_hi, x_lo], B2 = [x_hi, 1.0]
            int b1[4], b2[4];
            {
                const float xs[4] = {xf0.x, xf0.y, xf0.z, xf0.w};
#pragma unroll
                for (int f = 0; f < 4; ++f) {
                    const unsigned th = __float_as_uint(xs[f]) & 0xFFFF0000u;
                    const float lo = xs[f] - __uint_as_float(th);
                    b1[f] = (int)((th >> 16) | (__float_as_uint(lo) & 0xFFFF0000u));
                    b2[f] = (int)((th >> 16) | 0x3F800000u);
                }
            }
            const short8 B1 = __builtin_bit_cast(short8, make_int4(b1[0], b1[1], b1[2], b1[3]));
            const short8 B2 = __builtin_bit_cast(short8, make_int4(b2[0], b2[1], b2[2], b2[3]));

            f32x4 acc[KK];
#pragma unroll
            for (int k = 0; k < KK; ++k) acc[k] = (f32x4){0.0f, 0.0f, 0.0f, 0.0f};
#pragma unroll
            for (int k = 0; k < KK; ++k)
                acc[k] = __builtin_amdgcn_mfma_f32_16x16x32_bf16(A1[k], B1, acc[k], 0, 0, 0);
#pragma unroll
            for (int k = 0; k < KK; ++k)
                acc[k] = __builtin_amdgcn_mfma_f32_16x16x32_bf16(A2[k], B2, acc[k], 0, 0, 0);

            float pr[KK];
#pragma unroll
            for (int k = 0; k < KK; ++k) {
                float s = acc[k][0] * acc[k][0];
                s = fmaf(acc[k][1], acc[k][1], s);
                s = fmaf(acc[k][2], acc[k][2], s);
                s = fmaf(acc[k][3], acc[k][3], s);
#if __has_builtin(__builtin_amdgcn_permlane16_swap)
                {
                    auto r = __builtin_amdgcn_permlane16_swap(__float_as_uint(s), __float_as_uint(s), false, false);
                    s = __uint_as_float(r[0]) + __uint_as_float(r[1]);
                    auto r2 = __builtin_amdgcn_permlane32_swap(__float_as_uint(s), __float_as_uint(s), false, false);
                    s = __uint_as_float(r2[0]) + __uint_as_float(r2[1]);
                }
#else
                s += __shfl_xor(s, 16, 64);
                s += __shfl_xor(s, 32, 64);
#endif
                pr[k] = EXP2F(c0v[k] - s);
            }
            const float s01 = fmaf(pr[1], pr[1], pr[0] * pr[0]);
            const float s23 = fmaf(pr[3], pr[3], pr[2] * pr[2]);
            const float s45 = fmaf(pr[5], pr[5], pr[4] * pr[4]);
            const float s67 = fmaf(pr[7], pr[7], pr[6] * pr[6]);
            const float ss = (s01 + s23) + (s45 + s67);
            const float inv = rsqrtf(fmaxf(ss, 1e-12f));

            if (lane < 32) {                      // stage probs: g==0 -> slot+4, g==1 -> slot+5
                f32x4 pv;
                if (g == 0) pv = (f32x4){pr[0] * inv, pr[1] * inv, pr[2] * inv, pr[3] * inv};
                else        pv = (f32x4){pr[4] * inv, pr[5] * inv, pr[6] * inv, pr[7] * inv};
                sw[6 * pp + 4 + g] = pv;
            }

            xf0 = xf1; xf1 = xf2;
        }

        // ---- flush pair: 3 x 1024B lane-linear contiguous stores ----
        float* og = obase + (size_t)pi * 768;     // 32 px * 24 floats
#pragma unroll
        for (int q = 0; q < 3; ++q) {
            const f32x4 v = sw[q * 64 + lane];    // intra-wave DS in-order: no barrier
            *(f32x4*)(og + q * 256) = v;
        }
    }
}

extern "C" void kernel_launch(void* const* d_in, const int* in_sizes, int n_in,
                              void* d_out, int out_size, void* d_ws, size_t ws_size,
                              hipStream_t stream) {
    const float* x    = (const float*)d_in[0];   // [B,H,W,C] fp32
    const float* mean = (const float*)d_in[1];   // [K,C] fp32
    const float* st   = (const float*)d_in[2];   // [K,C,C] fp32
    float* out = (float*)d_out;                  // [B,H,W,C+K] fp32

    fuzzy_kernel<<<GRID, TPB, 0, stream>>>(x, mean, st, out);

    // diagnostic control: same traffic shape into d_ws (never touches d_out)
    if (ws_size >= (size_t)NPIX * 24 * sizeof(float))
        ctrl_kernel<<<NPIX / 256, 256, 0, stream>>>(x, (float*)d_ws);
}

// Round 11
// 22.336 us; speedup vs baseline: 2.0011x; 2.0011x over previous
//
#include <hip/hip_runtime.h>
#include <math.h>

#define NPIX (8 * 256 * 256)   // B*H*W
#define CC 16                  // C
#define KK 8                   // K classes
#define TPB 256                // 4 independent waves
#define NTILES 16              // 16-px tiles per wave -> 256 px/wave, 1024 px/block
#define GRID (NPIX / 1024)     // 512 blocks = 2 resident/CU

typedef __attribute__((ext_vector_type(8))) short short8;  // 8 bf16 (4 VGPRs)
typedef __attribute__((ext_vector_type(4))) float f32x4;

#if __has_builtin(__builtin_amdgcn_exp2f)
#define EXP2F(v) __builtin_amdgcn_exp2f(v)
#else
#define EXP2F(v) exp2f(v)
#endif

// prob_k = exp2(c0_k - sum_i z_i^2), z = SC*Linv*x - SC*Linv*mean,
// z via MFMA(A1,[x_hi,x_lo]) + MFMA(A2,[x_hi,1.0]);  SC = sqrt(0.5*log2 e).
// A1 = [W_hi,W_hi]; A2 = [W_lo, biasslot] (bias hi/lo in g==0, f<2 odd slots).
// Identical to R9 except: flush stores are NONTEMPORAL (streaming write-once output).

__global__ __launch_bounds__(TPB, 2) void fuzzy_kernel(const float* __restrict__ x,
                                                       const float* __restrict__ mean,
                                                       const float* __restrict__ st,
                                                       float* __restrict__ out) {
    __shared__ float linv[KK][CC][CC + 1];   // unscaled tril inverse
    __shared__ float bias[KK][CC];           // -SC*(Linv*mean)
    __shared__ int4  a1buf[KK * 64];
    __shared__ int4  a2buf[KK * 64];
    __shared__ float c0buf[KK];
    __shared__ f32x4 stgv[4][192];           // per-wave store staging: 32px * 96B

    const int t = threadIdx.x, lane = t & 63, wid = t >> 6;

    // ---- setup phase A: tril inverse (t<128); c0 (t=128..135) ----
    if (t < 128) {
        const int k = t >> 4, j = t & 15;
        const float* L = st + k * CC * CC;
        float col[CC];
#pragma unroll
        for (int i = 0; i < CC; ++i) {
            float s = (i == j) ? 1.0f : 0.0f;
#pragma unroll
            for (int m = 0; m < i; ++m) s = fmaf(-L[i * CC + m], col[m], s);
            col[i] = (i < j) ? 0.0f : s / L[i * CC + i];
            linv[k][i][j] = col[i];
        }
    } else if (t < 128 + KK) {
        const int k = t - 128;
        const float* Lk = st + k * CC * CC;
        float ld = 0.0f;
#pragma unroll
        for (int i = 0; i < CC; ++i) ld += __logf(fabsf(Lk[i * CC + i]));
        c0buf[k] = (-14.70301653f - ld) * 1.44269504f;  // -0.5*16*ln(2pi), log2(e)
    }
    __syncthreads();

    const float SCALE = 0.8493218891f;       // sqrt(0.5*log2(e))
    // ---- setup phase B1: bias rows (t<128) ----
    if (t < 128) {
        const int k = t >> 4, j = t & 15;
        float b = 0.0f;
#pragma unroll
        for (int j2 = 0; j2 < CC; ++j2) b = fmaf(linv[k][j][j2], mean[k * CC + j2], b);
        bias[k][j] = -b * SCALE;
    }
    __syncthreads();

    // ---- setup phase B2: pack fragments, 2 slots per thread ----
#pragma unroll
    for (int q = 0; q < 2; ++q) {
        const int idx = t * 2 + q;
        const int kk2 = idx >> 6, l = idx & 63;
        const int i = l & 15, gg = l >> 4;
        int a1d[4], a2d[4];
#pragma unroll
        for (int f = 0; f < 4; ++f) {
            const float w = SCALE * linv[kk2][i][4 * gg + f];
            const unsigned wb = __float_as_uint(w) & 0xFFFF0000u;
            const unsigned hb = wb >> 16;
            a1d[f] = (int)(hb | (hb << 16));                       // [W_hi, W_hi]
            const float wl = w - __uint_as_float(wb);
            unsigned odd = 0u;
            if (gg == 0 && f < 2) {                                // bias hi/lo slots
                const float b = bias[kk2][i];
                const unsigned bb = __float_as_uint(b) & 0xFFFF0000u;
                if (f == 0) odd = bb >> 16;
                else        odd = __float_as_uint(b - __uint_as_float(bb)) >> 16;
            }
            a2d[f] = (int)((__float_as_uint(wl) >> 16) | (odd << 16));  // [W_lo, bias]
        }
        a1buf[idx] = make_int4(a1d[0], a1d[1], a1d[2], a1d[3]);
        a2buf[idx] = make_int4(a2d[0], a2d[1], a2d[2], a2d[3]);
    }
    __syncthreads();

    // ---- hoist A fragments + c0 into registers ----
    short8 A1[KK], A2[KK];
    float c0v[KK];
#pragma unroll
    for (int k = 0; k < KK; ++k) {
        A1[k]  = __builtin_bit_cast(short8, a1buf[k * 64 + lane]);
        A2[k]  = __builtin_bit_cast(short8, a2buf[k * 64 + lane]);
        c0v[k] = c0buf[k];
    }

    const int p = lane & 15, g = lane >> 4;
    const size_t wbase = (size_t)blockIdx.x * 1024 + (size_t)wid * 256;  // wave pixel base
    const float* xptr = x + (wbase + p) * CC + g * 4;                    // + tt*256
    float* obase = out + wbase * 24 + (size_t)lane * 4;                  // lane-linear store base
    f32x4* sw = stgv[wid];

    float4 xf0 = *(const float4*)(xptr);
    float4 xf1 = *(const float4*)(xptr + 256);

#pragma unroll
    for (int pi = 0; pi < NTILES / 2; ++pi) {
#pragma unroll
        for (int sub = 0; sub < 2; ++sub) {
            const int tt = 2 * pi + sub;
            const float4 xf2 = (tt + 2 < NTILES) ? *(const float4*)(xptr + (size_t)(tt + 2) * 256) : xf0;

            const int pp = sub * 16 + p;          // pixel within the 32-px pair
            sw[6 * pp + g] = __builtin_bit_cast(f32x4, xf0);   // stage x passthrough

            // pack B1 = [x_hi, x_lo], B2 = [x_hi, 1.0]
            int b1[4], b2[4];
            {
                const float xs[4] = {xf0.x, xf0.y, xf0.z, xf0.w};
#pragma unroll
                for (int f = 0; f < 4; ++f) {
                    const unsigned th = __float_as_uint(xs[f]) & 0xFFFF0000u;
                    const float lo = xs[f] - __uint_as_float(th);
                    b1[f] = (int)((th >> 16) | (__float_as_uint(lo) & 0xFFFF0000u));
                    b2[f] = (int)((th >> 16) | 0x3F800000u);
                }
            }
            const short8 B1 = __builtin_bit_cast(short8, make_int4(b1[0], b1[1], b1[2], b1[3]));
            const short8 B2 = __builtin_bit_cast(short8, make_int4(b2[0], b2[1], b2[2], b2[3]));

            f32x4 acc[KK];
#pragma unroll
            for (int k = 0; k < KK; ++k) acc[k] = (f32x4){0.0f, 0.0f, 0.0f, 0.0f};
#pragma unroll
            for (int k = 0; k < KK; ++k)
                acc[k] = __builtin_amdgcn_mfma_f32_16x16x32_bf16(A1[k], B1, acc[k], 0, 0, 0);
#pragma unroll
            for (int k = 0; k < KK; ++k)
                acc[k] = __builtin_amdgcn_mfma_f32_16x16x32_bf16(A2[k], B2, acc[k], 0, 0, 0);

            float pr[KK];
#pragma unroll
            for (int k = 0; k < KK; ++k) {
                float s = acc[k][0] * acc[k][0];
                s = fmaf(acc[k][1], acc[k][1], s);
                s = fmaf(acc[k][2], acc[k][2], s);
                s = fmaf(acc[k][3], acc[k][3], s);
#if __has_builtin(__builtin_amdgcn_permlane16_swap)
                {
                    auto r = __builtin_amdgcn_permlane16_swap(__float_as_uint(s), __float_as_uint(s), false, false);
                    s = __uint_as_float(r[0]) + __uint_as_float(r[1]);
                    auto r2 = __builtin_amdgcn_permlane32_swap(__float_as_uint(s), __float_as_uint(s), false, false);
                    s = __uint_as_float(r2[0]) + __uint_as_float(r2[1]);
                }
#else
                s += __shfl_xor(s, 16, 64);
                s += __shfl_xor(s, 32, 64);
#endif
                pr[k] = EXP2F(c0v[k] - s);
            }
            const float s01 = fmaf(pr[1], pr[1], pr[0] * pr[0]);
            const float s23 = fmaf(pr[3], pr[3], pr[2] * pr[2]);
            const float s45 = fmaf(pr[5], pr[5], pr[4] * pr[4]);
            const float s67 = fmaf(pr[7], pr[7], pr[6] * pr[6]);
            const float ss = (s01 + s23) + (s45 + s67);
            const float inv = rsqrtf(fmaxf(ss, 1e-12f));

            if (lane < 32) {                      // stage probs: g==0 -> slot+4, g==1 -> slot+5
                f32x4 pv;
                if (g == 0) pv = (f32x4){pr[0] * inv, pr[1] * inv, pr[2] * inv, pr[3] * inv};
                else        pv = (f32x4){pr[4] * inv, pr[5] * inv, pr[6] * inv, pr[7] * inv};
                sw[6 * pp + 4 + g] = pv;
            }

            xf0 = xf1; xf1 = xf2;
        }

        // ---- flush pair: 3 x 1024B lane-linear contiguous NONTEMPORAL stores ----
        float* og = obase + (size_t)pi * 768;     // 32 px * 24 floats
#pragma unroll
        for (int q = 0; q < 3; ++q) {
            const f32x4 v = sw[q * 64 + lane];    // intra-wave DS in-order: no barrier
            __builtin_nontemporal_store(v, (f32x4*)(og + q * 256));
        }
    }
}

extern "C" void kernel_launch(void* const* d_in, const int* in_sizes, int n_in,
                              void* d_out, int out_size, void* d_ws, size_t ws_size,
                              hipStream_t stream) {
    const float* x    = (const float*)d_in[0];   // [B,H,W,C] fp32
    const float* mean = (const float*)d_in[1];   // [K,C] fp32
    const float* st   = (const float*)d_in[2];   // [K,C,C] fp32
    float* out = (float*)d_out;                  // [B,H,W,C+K] fp32

    fuzzy_kernel<<<GRID, TPB, 0, stream>>>(x, mean, st, out);
}